// Round 8
// baseline (185.550 us; speedup 1.0000x reference)
//
#include <hip/hip_runtime.h>

typedef _Float16 half_t;
typedef _Float16 half8  __attribute__((ext_vector_type(8)));
typedef _Float16 half4v __attribute__((ext_vector_type(4)));
typedef float    f32x16 __attribute__((ext_vector_type(16)));
typedef float    f32x4  __attribute__((ext_vector_type(4)));

#define DEVI static __device__ __forceinline__

constexpr int B_  = 16384;
constexpr int T_  = 28;
constexpr int IN_ = 28;
constexpr int H_  = 128;
constexpr int C_  = 11;
constexpr int BT  = 64;    // batch rows per block; grid = 256 = 1 block/CU
constexpr int NT  = 768;   // 12 waves: 4x L0, 4x L1, 4x L2 -> 3 waves/SIMD, one per layer
constexpr int HSTR = 136;  // LDS stride (halves): 272B rows, 16B-aligned, conflict-free b128

constexpr int HBUF = BT * HSTR;       // halves per h buffer
constexpr int SM_HALVES = 6 * HBUF;   // h[3][2]; x no longer staged in LDS
constexpr size_t SM_BYTES = (size_t)SM_HALVES * 2 + 3 * H_ * 4;  // 105984 B

DEVI f32x16 mfma(half8 a, half8 b, f32x16 c) {
  return __builtin_amdgcn_mfma_f32_32x32x16_f16(a, b, c, 0, 0, 0);
}

DEVI half8 frag(const half_t* base, int kc) { return *(const half8*)(base + kc * 16); }

DEVI half8 cvt8(f32x4 a, f32x4 b) {
  half8 f;
#pragma unroll
  for (int j = 0; j < 4; ++j) { f[j] = (half_t)a[j]; f[4 + j] = (half_t)b[j]; }
  return f;
}

// A-fragments, one 32-row m-tile of a 128x128 row-major fp32 matrix.
// A layout (32x32x16 f16, validated): lane holds A[m=lane&31][k=(lane>>5)*8+j].
DEVI void loadw8(half8 d[8], const float* __restrict__ w, int mrow, int hf) {
  const float* p = w + mrow * H_ + hf * 8;
#pragma unroll
  for (int kc = 0; kc < 8; ++kc) {
    half8 f;
#pragma unroll
    for (int j = 0; j < 8; ++j) f[j] = (half_t)p[kc * 16 + j];
    d[kc] = f;
  }
}

// Per-wave accumulator bias init: binit[rq*4+ri] = bias[mrow0 + rq*8 + hf*4 + ri].
DEVI f32x16 loadbias(const float* __restrict__ bl, int mrow0, int hf) {
  f32x16 b;
#pragma unroll
  for (int rq = 0; rq < 4; ++rq) {
    const f32x4 b4 = *(const f32x4*)&bl[mrow0 + rq * 8 + hf * 4];
#pragma unroll
    for (int ri = 0; ri < 4; ++ri) b[rq * 4 + ri] = b4[ri];
  }
  return b;
}

// Packed epilogue: h = relu(acc) -> hout (bias already inside acc).
// C/D layout (HW-verified m74/m101): col=lane&31, row=(reg&3)+8*(reg>>2)+4*(lane>>5).
DEVI void epi2(half_t* __restrict__ hout, f32x16 a, int mrow0, int ncol0,
               int l31, int hf) {
  const half4v z = {};
#pragma unroll
  for (int rq = 0; rq < 4; ++rq) {
    const int n0 = mrow0 + rq * 8 + hf * 4;
    half4v h4;
#pragma unroll
    for (int ri = 0; ri < 4; ++ri) h4[ri] = (half_t)a[rq * 4 + ri];
    h4 = __builtin_elementwise_max(h4, z);
    *(half4v*)&hout[(ncol0 + l31) * HSTR + n0] = h4;
  }
}

// R8 = R7 (proven 83.5us) + (a) x B-frags built directly from global, prefetched
// one iter ahead in regs (deletes 16 LDS reads + all x staging; ai0's zero-pad
// for k>=28 makes the unmasked B tail a don't-care; 2nd quad addr-clamped to
// stay in-row -> no OOB), + (b) s_setprio(1) around MFMA clusters (T5).
__global__ __launch_bounds__(NT) __attribute__((amdgpu_waves_per_eu(3)))
void rnn_pipe(const float* __restrict__ x,
              const float* __restrict__ wih0, const float* __restrict__ whh0,
              const float* __restrict__ bih0, const float* __restrict__ bhh0,
              const float* __restrict__ wih1, const float* __restrict__ whh1,
              const float* __restrict__ bih1, const float* __restrict__ bhh1,
              const float* __restrict__ wih2, const float* __restrict__ whh2,
              const float* __restrict__ bih2, const float* __restrict__ bhh2,
              const float* __restrict__ fcw, const float* __restrict__ fcb,
              float* __restrict__ out)
{
  extern __shared__ __align__(16) char smraw[];
  half_t* hs   = (half_t*)smraw;
  float*  bias = (float*)(hs + SM_HALVES);
#define HB(l, b) (hs + ((l) * 2 + (b)) * HBUF)

  const int tid  = threadIdx.x;
  const int b0   = blockIdx.x * BT;
  const int lane = tid & 63;
  const int wid  = tid >> 6;
  const int l31  = lane & 31;
  const int hf   = lane >> 5;

  // ---- init: zero h buffers (h_{-1}=0), stage biases ----
  for (int i = tid; i < SM_HALVES / 2; i += NT) ((unsigned int*)hs)[i] = 0u;
  if (tid < H_) {
    bias[tid]          = bih0[tid] + bhh0[tid];
    bias[H_ + tid]     = bih1[tid] + bhh1[tid];
    bias[2 * H_ + tid] = bih2[tid] + bhh2[tid];
  }
  __syncthreads();

  // ===== wave-specialized pipeline: iter i computes h0[i], h1[i-1], h2[i-2] =====
  // Reads hit parity p, writes parity np: ONE barrier/iter; 30 barriers per branch.
  if (wid < 4) {
    // ---- L0: 1 m-tile, 2 n-tiles; x B-frags direct from global, reg dbuf ----
    const int mt = wid;
    half8 ai0[2], ah0[8];
    loadw8(ah0, whh0, mt * 32 + l31, hf);
#pragma unroll
    for (int kc = 0; kc < 2; ++kc) {  // wih0: K=28 padded to 32 with zeros
      half8 f;
#pragma unroll
      for (int j = 0; j < 8; ++j) {
        const int k = kc * 16 + hf * 8 + j;
        f[j] = (k < IN_) ? (half_t)wih0[(mt * 32 + l31) * IN_ + k] : (half_t)0.0f;
      }
      ai0[kc] = f;
    }
    const f32x16 binit = loadbias(bias, mt * 32, hf);
    // per-lane x row bases and intra-row offsets (2nd quad clamped in-row)
    const float* xr0 = x + (size_t)(b0 + l31) * (T_ * IN_);
    const float* xr1 = xr0 + (size_t)32 * (T_ * IN_);
    const int k0a = hf * 8,      k0b = k0a + 4;                      // kc=0: <=15
    const int k1a = 16 + hf * 8, k1b = (k1a + 4 > 24) ? 24 : k1a + 4; // kc=1 clamp
    half8 fx0[2], fx1[2];  // current-iter x B-frags (tile0/tile1, kc 0..1)
    {  // prime t=0
      const float* A0 = xr0; const float* A1 = xr1;
      fx0[0] = cvt8(*(const f32x4*)(A0 + k0a), *(const f32x4*)(A0 + k0b));
      fx0[1] = cvt8(*(const f32x4*)(A0 + k1a), *(const f32x4*)(A0 + k1b));
      fx1[0] = cvt8(*(const f32x4*)(A1 + k0a), *(const f32x4*)(A1 + k0b));
      fx1[1] = cvt8(*(const f32x4*)(A1 + k1a), *(const f32x4*)(A1 + k1b));
    }
    for (int ib = 0; ib < (T_ + 2) / 2; ++ib) {
#pragma unroll
      for (int pp = 0; pp < 2; ++pp) {
        const int i = ib * 2 + pp;
        const int p = pp, np = pp ^ 1;
        const bool xn = (i + 1 < T_);
        f32x4 q00, q01, q10, q11, q20, q21, q30, q31;
        if (xn) {  // issue next-iter x loads early; converted after compute
          const float* A0 = xr0 + (size_t)(i + 1) * IN_;
          const float* A1 = xr1 + (size_t)(i + 1) * IN_;
          q00 = *(const f32x4*)(A0 + k0a); q01 = *(const f32x4*)(A0 + k0b);
          q10 = *(const f32x4*)(A0 + k1a); q11 = *(const f32x4*)(A0 + k1b);
          q20 = *(const f32x4*)(A1 + k0a); q21 = *(const f32x4*)(A1 + k0b);
          q30 = *(const f32x4*)(A1 + k1a); q31 = *(const f32x4*)(A1 + k1b);
        }
        if (i < T_) {
          const half_t* bh0 = HB(0, p) + l31 * HSTR + hf * 8;
          const half_t* bh1 = HB(0, p) + (32 + l31) * HSTR + hf * 8;
          f32x16 a0 = binit, a1 = binit;
          __builtin_amdgcn_s_setprio(1);
#pragma unroll
          for (int kc = 0; kc < 2; ++kc) {
            a0 = mfma(ai0[kc], fx0[kc], a0);
            a1 = mfma(ai0[kc], fx1[kc], a1);
          }
#pragma unroll
          for (int kc = 0; kc < 8; ++kc) {
            a0 = mfma(ah0[kc], frag(bh0, kc), a0);
            a1 = mfma(ah0[kc], frag(bh1, kc), a1);
          }
          __builtin_amdgcn_s_setprio(0);
          epi2(HB(0, np), a0, mt * 32, 0,  l31, hf);
          epi2(HB(0, np), a1, mt * 32, 32, l31, hf);
        }
        if (xn) {  // convert next-iter frags (off critical path, reg-private)
          fx0[0] = cvt8(q00, q01); fx0[1] = cvt8(q10, q11);
          fx1[0] = cvt8(q20, q21); fx1[1] = cvt8(q30, q31);
        }
        __syncthreads();
      }
    }
  } else if (wid < 8) {
    // ---- L1: 1 m-tile, 2 n-tiles ----
    const int mt1 = wid - 4;
    half8 wi[8], wh[8];
    loadw8(wi, wih1, mt1 * 32 + l31, hf);
    loadw8(wh, whh1, mt1 * 32 + l31, hf);
    const f32x16 binit = loadbias(bias + H_, mt1 * 32, hf);
    for (int ib = 0; ib < (T_ + 2) / 2; ++ib) {
#pragma unroll
      for (int pp = 0; pp < 2; ++pp) {
        const int i = ib * 2 + pp;
        const int p = pp, np = pp ^ 1;
        if (i >= 1 && i < T_ + 1) {
          const half_t* bi0 = HB(0, p) + l31 * HSTR + hf * 8;        // input h0[t=i-1]
          const half_t* bi1 = HB(0, p) + (32 + l31) * HSTR + hf * 8;
          const half_t* br0 = HB(1, p) + l31 * HSTR + hf * 8;        // recurrent h1[t=i-2]
          const half_t* br1 = HB(1, p) + (32 + l31) * HSTR + hf * 8;
          f32x16 a0 = binit, a1 = binit;
          __builtin_amdgcn_s_setprio(1);
#pragma unroll
          for (int kc = 0; kc < 8; ++kc) {
            a0 = mfma(wi[kc], frag(bi0, kc), a0);
            a1 = mfma(wi[kc], frag(bi1, kc), a1);
          }
#pragma unroll
          for (int kc = 0; kc < 8; ++kc) {
            a0 = mfma(wh[kc], frag(br0, kc), a0);
            a1 = mfma(wh[kc], frag(br1, kc), a1);
          }
          __builtin_amdgcn_s_setprio(0);
          epi2(HB(1, np), a0, mt1 * 32, 0,  l31, hf);
          epi2(HB(1, np), a1, mt1 * 32, 32, l31, hf);
        }
        __syncthreads();
      }
    }
  } else {
    // ---- L2: 1 m-tile, 2 n-tiles ----
    const int mt2 = wid - 8;
    half8 wi[8], wh[8];
    loadw8(wi, wih2, mt2 * 32 + l31, hf);
    loadw8(wh, whh2, mt2 * 32 + l31, hf);
    const f32x16 binit = loadbias(bias + 2 * H_, mt2 * 32, hf);
    for (int ib = 0; ib < (T_ + 2) / 2; ++ib) {
#pragma unroll
      for (int pp = 0; pp < 2; ++pp) {
        const int i = ib * 2 + pp;
        const int p = pp, np = pp ^ 1;
        if (i >= 2) {
          const half_t* bi0 = HB(1, p) + l31 * HSTR + hf * 8;        // input h1[t=i-2]
          const half_t* bi1 = HB(1, p) + (32 + l31) * HSTR + hf * 8;
          const half_t* br0 = HB(2, p) + l31 * HSTR + hf * 8;        // recurrent h2[t=i-3]
          const half_t* br1 = HB(2, p) + (32 + l31) * HSTR + hf * 8;
          f32x16 a0 = binit, a1 = binit;
          __builtin_amdgcn_s_setprio(1);
#pragma unroll
          for (int kc = 0; kc < 8; ++kc) {
            a0 = mfma(wi[kc], frag(bi0, kc), a0);
            a1 = mfma(wi[kc], frag(bi1, kc), a1);
          }
#pragma unroll
          for (int kc = 0; kc < 8; ++kc) {
            a0 = mfma(wh[kc], frag(br0, kc), a0);
            a1 = mfma(wh[kc], frag(br1, kc), a1);
          }
          __builtin_amdgcn_s_setprio(0);
          epi2(HB(2, np), a0, mt2 * 32, 0,  l31, hf);
          epi2(HB(2, np), a1, mt2 * 32, 32, l31, hf);
        }
        __syncthreads();
      }
    }
  }
  // last in-loop barrier (i=29) makes final h2 (parity 0) visible

  // ---- FC head: out[b][c] = h2_last[b] . fcw[c] + fcb[c] ----
  if (tid < 512) {
    const half_t* h2f = HB(2, 0);
    const int row = tid >> 3, q = tid & 7;
    for (int c = q; c < C_; c += 8) {
      float s = fcb[c];
      const float* wp = fcw + c * H_;
#pragma unroll
      for (int k = 0; k < H_; k += 8) {
        const half8 hv = *(const half8*)&h2f[row * HSTR + k];
#pragma unroll
        for (int j = 0; j < 8; ++j) s += (float)hv[j] * wp[k + j];
      }
      out[(size_t)(b0 + row) * C_ + c] = s;
    }
  }
#undef HB
}

extern "C" void kernel_launch(void* const* d_in, const int* in_sizes, int n_in,
                              void* d_out, int out_size, void* d_ws, size_t ws_size,
                              hipStream_t stream)
{
  const float* x    = (const float*)d_in[0];
  const float* wih0 = (const float*)d_in[1];
  const float* whh0 = (const float*)d_in[2];
  const float* bih0 = (const float*)d_in[3];
  const float* bhh0 = (const float*)d_in[4];
  const float* wih1 = (const float*)d_in[5];
  const float* whh1 = (const float*)d_in[6];
  const float* bih1 = (const float*)d_in[7];
  const float* bhh1 = (const float*)d_in[8];
  const float* wih2 = (const float*)d_in[9];
  const float* whh2 = (const float*)d_in[10];
  const float* bih2 = (const float*)d_in[11];
  const float* bhh2 = (const float*)d_in[12];
  const float* fcw  = (const float*)d_in[13];
  const float* fcb  = (const float*)d_in[14];
  float* out = (float*)d_out;

  (void)hipFuncSetAttribute((const void*)rnn_pipe,
                            hipFuncAttributeMaxDynamicSharedMemorySize, (int)SM_BYTES);

  rnn_pipe<<<B_ / BT, NT, SM_BYTES, stream>>>(x,
      wih0, whh0, bih0, bhh0,
      wih1, whh1, bih1, bhh1,
      wih2, whh2, bih2, bhh2,
      fcw, fcb, out);
}

// Round 9
// 175.181 us; speedup vs baseline: 1.0592x; 1.0592x over previous
//
#include <hip/hip_runtime.h>

typedef _Float16 half_t;
typedef _Float16 half8  __attribute__((ext_vector_type(8)));
typedef _Float16 half4v __attribute__((ext_vector_type(4)));
typedef float    f32x16 __attribute__((ext_vector_type(16)));
typedef float    f32x4  __attribute__((ext_vector_type(4)));

#define DEVI static __device__ __forceinline__

constexpr int B_  = 16384;
constexpr int T_  = 28;
constexpr int IN_ = 28;
constexpr int H_  = 128;
constexpr int C_  = 11;
constexpr int BT  = 64;    // batch rows per block; grid = 256 = 1 block/CU
constexpr int NT  = 768;   // 12 waves: 4x L0, 4x L1, 4x L2 -> 3 waves/SIMD, one per layer
constexpr int HSTR = 136;  // LDS stride (halves): 272B rows, 16B-aligned, conflict-free b128
constexpr int XSTR = 40;

constexpr int HBUF = BT * HSTR;                 // halves per h buffer
constexpr int XBUF = BT * XSTR;                 // halves per x buffer
constexpr int SM_HALVES = 6 * HBUF + 2 * XBUF;  // h[3][2] + xin[2]
constexpr size_t SM_BYTES = (size_t)SM_HALVES * 2 + 3 * H_ * 4;  // + bias = 116224 B

DEVI f32x16 mfma(half8 a, half8 b, f32x16 c) {
  return __builtin_amdgcn_mfma_f32_32x32x16_f16(a, b, c, 0, 0, 0);
}

DEVI half8 frag(const half_t* base, int kc) { return *(const half8*)(base + kc * 16); }

// A-fragments, one 32-row m-tile of a 128x128 row-major fp32 matrix.
// A layout (32x32x16 f16, validated): lane holds A[m=lane&31][k=(lane>>5)*8+j].
DEVI void loadw8(half8 d[8], const float* __restrict__ w, int mrow, int hf) {
  const float* p = w + mrow * H_ + hf * 8;
#pragma unroll
  for (int kc = 0; kc < 8; ++kc) {
    half8 f;
#pragma unroll
    for (int j = 0; j < 8; ++j) f[j] = (half_t)p[kc * 16 + j];
    d[kc] = f;
  }
}

// Per-wave accumulator bias init: binit[rq*4+ri] = bias[mrow0 + rq*8 + hf*4 + ri].
// Bias is folded into the MFMA C-input (f32 add, same numerics as epilogue add).
DEVI f32x16 loadbias(const float* __restrict__ bl, int mrow0, int hf) {
  f32x16 b;
#pragma unroll
  for (int rq = 0; rq < 4; ++rq) {
    const f32x4 b4 = *(const f32x4*)&bl[mrow0 + rq * 8 + hf * 4];
#pragma unroll
    for (int ri = 0; ri < 4; ++ri) b[rq * 4 + ri] = b4[ri];
  }
  return b;
}

// Packed epilogue: h = relu(acc) -> hout (bias already inside acc).
// RTE scalar cvt (matches prior rounding), then packed f16 max (v_pk_max_f16).
// C/D layout (HW-verified m74/m101): col=lane&31, row=(reg&3)+8*(reg>>2)+4*(lane>>5).
DEVI void epi2(half_t* __restrict__ hout, f32x16 a, int mrow0, int ncol0,
               int l31, int hf) {
  const half4v z = {};
#pragma unroll
  for (int rq = 0; rq < 4; ++rq) {
    const int n0 = mrow0 + rq * 8 + hf * 4;
    half4v h4;
#pragma unroll
    for (int ri = 0; ri < 4; ++ri) h4[ri] = (half_t)a[rq * 4 + ri];
    h4 = __builtin_elementwise_max(h4, z);
    *(half4v*)&hout[(ncol0 + l31) * HSTR + n0] = h4;
  }
}

// R9 = R7 (proven 83.5us: bias-in-acc, packed relu, x2 unroll, LDS x-staging)
// + ONE change: s_setprio(1) around the MFMA clusters (T5, isolated test).
__global__ __launch_bounds__(NT) __attribute__((amdgpu_waves_per_eu(3)))
void rnn_pipe(const float* __restrict__ x,
              const float* __restrict__ wih0, const float* __restrict__ whh0,
              const float* __restrict__ bih0, const float* __restrict__ bhh0,
              const float* __restrict__ wih1, const float* __restrict__ whh1,
              const float* __restrict__ bih1, const float* __restrict__ bhh1,
              const float* __restrict__ wih2, const float* __restrict__ whh2,
              const float* __restrict__ bih2, const float* __restrict__ bhh2,
              const float* __restrict__ fcw, const float* __restrict__ fcb,
              float* __restrict__ out)
{
  extern __shared__ __align__(16) char smraw[];
  half_t* hs   = (half_t*)smraw;
  float*  bias = (float*)(hs + SM_HALVES);
#define HB(l, b) (hs + ((l) * 2 + (b)) * HBUF)
#define XB(b)    (hs + 6 * HBUF + (b) * XBUF)

  const int tid  = threadIdx.x;
  const int b0   = blockIdx.x * BT;
  const int lane = tid & 63;
  const int wid  = tid >> 6;
  const int l31  = lane & 31;
  const int hf   = lane >> 5;

  // ---- init: zero all LDS buffers (h_{-1}=0, x pad cols=0), stage biases ----
  for (int i = tid; i < SM_HALVES / 2; i += NT) ((unsigned int*)hs)[i] = 0u;
  if (tid < H_) {
    bias[tid]          = bih0[tid] + bhh0[tid];
    bias[H_ + tid]     = bih1[tid] + bhh1[tid];
    bias[2 * H_ + tid] = bih2[tid] + bhh2[tid];
  }
  __syncthreads();
  if (tid < 512) {  // stage x[t=0] into XB(0): 64 rows x 7 f32x4 chunks
    const int row = tid >> 3, ch = tid & 7;
    if (ch < 7) {
      const f32x4 v = *(const f32x4*)(x + (size_t)(b0 + row) * (T_ * IN_) + ch * 4);
      half4v h4;
#pragma unroll
      for (int j = 0; j < 4; ++j) h4[j] = (half_t)v[j];
      *(half4v*)&XB(0)[row * XSTR + ch * 4] = h4;
    }
  }
  __syncthreads();

  // ===== wave-specialized pipeline: iter i computes h0[i], h1[i-1], h2[i-2] =====
  // Reads hit parity p, writes parity np: ONE barrier/iter; 30 barriers per branch.
  if (wid < 4) {
    // ---- L0: 1 m-tile, 2 n-tiles; also stages x[t=i+1] (tids 0..255) ----
    const int mt = wid;
    half8 ai0[2], ah0[8];
    loadw8(ah0, whh0, mt * 32 + l31, hf);
#pragma unroll
    for (int kc = 0; kc < 2; ++kc) {  // wih0: K=28 padded to 32 with zeros
      half8 f;
#pragma unroll
      for (int j = 0; j < 8; ++j) {
        const int k = kc * 16 + hf * 8 + j;
        f[j] = (k < IN_) ? (half_t)wih0[(mt * 32 + l31) * IN_ + k] : (half_t)0.0f;
      }
      ai0[kc] = f;
    }
    const f32x16 binit = loadbias(bias, mt * 32, hf);
    const int xrow = tid >> 3, xch = tid & 7;  // tid<256: rows 0..31 (+32 second chunk)
    for (int ib = 0; ib < (T_ + 2) / 2; ++ib) {
#pragma unroll
      for (int pp = 0; pp < 2; ++pp) {
        const int i = ib * 2 + pp;
        const int p = pp, np = pp ^ 1;
        const bool xact = (xch < 7) && (i + 1 < T_);
        f32x4 xq0, xq1;
        if (xact) {  // issue global loads early; consumed at iteration end
          const float* xp = x + (size_t)(i + 1) * IN_ + xch * 4;
          xq0 = *(const f32x4*)(xp + (size_t)(b0 + xrow) * (T_ * IN_));
          xq1 = *(const f32x4*)(xp + (size_t)(b0 + xrow + 32) * (T_ * IN_));
        }
        if (i < T_) {
          const half_t* bx0 = XB(p) + l31 * XSTR + hf * 8;
          const half_t* bx1 = XB(p) + (32 + l31) * XSTR + hf * 8;
          const half_t* bh0 = HB(0, p) + l31 * HSTR + hf * 8;
          const half_t* bh1 = HB(0, p) + (32 + l31) * HSTR + hf * 8;
          f32x16 a0 = binit, a1 = binit;
          __builtin_amdgcn_s_setprio(1);
#pragma unroll
          for (int kc = 0; kc < 2; ++kc) {
            a0 = mfma(ai0[kc], frag(bx0, kc), a0);
            a1 = mfma(ai0[kc], frag(bx1, kc), a1);
          }
#pragma unroll
          for (int kc = 0; kc < 8; ++kc) {
            a0 = mfma(ah0[kc], frag(bh0, kc), a0);
            a1 = mfma(ah0[kc], frag(bh1, kc), a1);
          }
          __builtin_amdgcn_s_setprio(0);
          epi2(HB(0, np), a0, mt * 32, 0,  l31, hf);
          epi2(HB(0, np), a1, mt * 32, 32, l31, hf);
        }
        if (xact) {
          half4v h4a, h4b;
#pragma unroll
          for (int j = 0; j < 4; ++j) { h4a[j] = (half_t)xq0[j]; h4b[j] = (half_t)xq1[j]; }
          *(half4v*)&XB(np)[xrow * XSTR + xch * 4] = h4a;
          *(half4v*)&XB(np)[(xrow + 32) * XSTR + xch * 4] = h4b;
        }
        __syncthreads();
      }
    }
  } else if (wid < 8) {
    // ---- L1: 1 m-tile, 2 n-tiles ----
    const int mt1 = wid - 4;
    half8 wi[8], wh[8];
    loadw8(wi, wih1, mt1 * 32 + l31, hf);
    loadw8(wh, whh1, mt1 * 32 + l31, hf);
    const f32x16 binit = loadbias(bias + H_, mt1 * 32, hf);
    for (int ib = 0; ib < (T_ + 2) / 2; ++ib) {
#pragma unroll
      for (int pp = 0; pp < 2; ++pp) {
        const int i = ib * 2 + pp;
        const int p = pp, np = pp ^ 1;
        if (i >= 1 && i < T_ + 1) {
          const half_t* bi0 = HB(0, p) + l31 * HSTR + hf * 8;        // input h0[t=i-1]
          const half_t* bi1 = HB(0, p) + (32 + l31) * HSTR + hf * 8;
          const half_t* br0 = HB(1, p) + l31 * HSTR + hf * 8;        // recurrent h1[t=i-2]
          const half_t* br1 = HB(1, p) + (32 + l31) * HSTR + hf * 8;
          f32x16 a0 = binit, a1 = binit;
          __builtin_amdgcn_s_setprio(1);
#pragma unroll
          for (int kc = 0; kc < 8; ++kc) {
            a0 = mfma(wi[kc], frag(bi0, kc), a0);
            a1 = mfma(wi[kc], frag(bi1, kc), a1);
          }
#pragma unroll
          for (int kc = 0; kc < 8; ++kc) {
            a0 = mfma(wh[kc], frag(br0, kc), a0);
            a1 = mfma(wh[kc], frag(br1, kc), a1);
          }
          __builtin_amdgcn_s_setprio(0);
          epi2(HB(1, np), a0, mt1 * 32, 0,  l31, hf);
          epi2(HB(1, np), a1, mt1 * 32, 32, l31, hf);
        }
        __syncthreads();
      }
    }
  } else {
    // ---- L2: 1 m-tile, 2 n-tiles ----
    const int mt2 = wid - 8;
    half8 wi[8], wh[8];
    loadw8(wi, wih2, mt2 * 32 + l31, hf);
    loadw8(wh, whh2, mt2 * 32 + l31, hf);
    const f32x16 binit = loadbias(bias + 2 * H_, mt2 * 32, hf);
    for (int ib = 0; ib < (T_ + 2) / 2; ++ib) {
#pragma unroll
      for (int pp = 0; pp < 2; ++pp) {
        const int i = ib * 2 + pp;
        const int p = pp, np = pp ^ 1;
        if (i >= 2) {
          const half_t* bi0 = HB(1, p) + l31 * HSTR + hf * 8;        // input h1[t=i-2]
          const half_t* bi1 = HB(1, p) + (32 + l31) * HSTR + hf * 8;
          const half_t* br0 = HB(2, p) + l31 * HSTR + hf * 8;        // recurrent h2[t=i-3]
          const half_t* br1 = HB(2, p) + (32 + l31) * HSTR + hf * 8;
          f32x16 a0 = binit, a1 = binit;
          __builtin_amdgcn_s_setprio(1);
#pragma unroll
          for (int kc = 0; kc < 8; ++kc) {
            a0 = mfma(wi[kc], frag(bi0, kc), a0);
            a1 = mfma(wi[kc], frag(bi1, kc), a1);
          }
#pragma unroll
          for (int kc = 0; kc < 8; ++kc) {
            a0 = mfma(wh[kc], frag(br0, kc), a0);
            a1 = mfma(wh[kc], frag(br1, kc), a1);
          }
          __builtin_amdgcn_s_setprio(0);
          epi2(HB(2, np), a0, mt2 * 32, 0,  l31, hf);
          epi2(HB(2, np), a1, mt2 * 32, 32, l31, hf);
        }
        __syncthreads();
      }
    }
  }
  // last in-loop barrier (i=29) makes final h2 (parity 0) visible

  // ---- FC head: out[b][c] = h2_last[b] . fcw[c] + fcb[c] ----
  if (tid < 512) {
    const half_t* h2f = HB(2, 0);
    const int row = tid >> 3, q = tid & 7;
    for (int c = q; c < C_; c += 8) {
      float s = fcb[c];
      const float* wp = fcw + c * H_;
#pragma unroll
      for (int k = 0; k < H_; k += 8) {
        const half8 hv = *(const half8*)&h2f[row * HSTR + k];
#pragma unroll
        for (int j = 0; j < 8; ++j) s += (float)hv[j] * wp[k + j];
      }
      out[(size_t)(b0 + row) * C_ + c] = s;
    }
  }
#undef HB
#undef XB
}

extern "C" void kernel_launch(void* const* d_in, const int* in_sizes, int n_in,
                              void* d_out, int out_size, void* d_ws, size_t ws_size,
                              hipStream_t stream)
{
  const float* x    = (const float*)d_in[0];
  const float* wih0 = (const float*)d_in[1];
  const float* whh0 = (const float*)d_in[2];
  const float* bih0 = (const float*)d_in[3];
  const float* bhh0 = (const float*)d_in[4];
  const float* wih1 = (const float*)d_in[5];
  const float* whh1 = (const float*)d_in[6];
  const float* bih1 = (const float*)d_in[7];
  const float* bhh1 = (const float*)d_in[8];
  const float* wih2 = (const float*)d_in[9];
  const float* whh2 = (const float*)d_in[10];
  const float* bih2 = (const float*)d_in[11];
  const float* bhh2 = (const float*)d_in[12];
  const float* fcw  = (const float*)d_in[13];
  const float* fcb  = (const float*)d_in[14];
  float* out = (float*)d_out;

  (void)hipFuncSetAttribute((const void*)rnn_pipe,
                            hipFuncAttributeMaxDynamicSharedMemorySize, (int)SM_BYTES);

  rnn_pipe<<<B_ / BT, NT, SM_BYTES, stream>>>(x,
      wih0, whh0, bih0, bhh0,
      wih1, whh1, bih1, bhh1,
      wih2, whh2, bih2, bhh2,
      fcw, fcb, out);
}